// Round 5
// baseline (2524.400 us; speedup 1.0000x reference)
//
#include <hip/hip_runtime.h>
#include <hip/hip_bf16.h>
#include <cstdint>
#include <cstddef>

// LSTM encoder: T=256, B=64, VOCAB=32000, E=512, H=1024
#define T_STEPS 256
#define BATCH   64
#define DE      512
#define DH      1024
#define NBLK    64     // recurrence blocks; each owns 16 hidden units (64 gate rows)

typedef short  bf16x8 __attribute__((ext_vector_type(8)));
typedef float  f32x4  __attribute__((ext_vector_type(4)));
typedef unsigned long long u64;

#define LSBMASK 0x0001000100010001ull

__device__ __forceinline__ unsigned short bf_bits(__hip_bfloat16 h) {
    union { __hip_bfloat16 h; unsigned short u; } x; x.h = h; return x.u;
}
__device__ __forceinline__ float b2f(unsigned short u) {
    union { float f; unsigned v; } x; x.v = ((unsigned)u) << 16; return x.f;
}

__device__ __forceinline__ void async_copy16(const void* gsrc, void* ldst) {
    __builtin_amdgcn_global_load_lds(
        (const __attribute__((address_space(1))) unsigned int*)gsrc,
        (__attribute__((address_space(3))) unsigned int*)ldst,
        16, 0, 0);
}

// relaxed agent-scope (LLC-coherent) accessors
__device__ __forceinline__ u64 llc_load64(const u64* p) {
    return __hip_atomic_load(p, __ATOMIC_RELAXED, __HIP_MEMORY_SCOPE_AGENT);
}
__device__ __forceinline__ void llc_store16(unsigned short* p, unsigned short v) {
    __hip_atomic_store(p, v, __ATOMIC_RELAXED, __HIP_MEMORY_SCOPE_AGENT);
}

// ---------------- h-buffer init: buf0 = h_0 = 0 (parity 0), buf1 = parity-1 poison ----------------
__global__ void k_init(u64* __restrict__ hbuf) {
    int i = blockIdx.x * 256 + threadIdx.x;        // 32768 u64 = 2 x 128 KB
    hbuf[i] = (i < 16384) ? 0ull : LSBMASK;
}

// ---------------- fp32 -> bf16 convert (8 elems/thread) ----------------
__global__ void k_f32_to_bf16(const float* __restrict__ src,
                              __hip_bfloat16* __restrict__ dst, int n8) {
    int i = blockIdx.x * blockDim.x + threadIdx.x;
    if (i >= n8) return;
    const float4* s = (const float4*)src + (size_t)i * 2;
    float4 a = s[0], b = s[1];
    union { unsigned short u[8]; uint4 v; } o;
    o.u[0] = bf_bits(__float2bfloat16(a.x));
    o.u[1] = bf_bits(__float2bfloat16(a.y));
    o.u[2] = bf_bits(__float2bfloat16(a.z));
    o.u[3] = bf_bits(__float2bfloat16(a.w));
    o.u[4] = bf_bits(__float2bfloat16(b.x));
    o.u[5] = bf_bits(__float2bfloat16(b.y));
    o.u[6] = bf_bits(__float2bfloat16(b.z));
    o.u[7] = bf_bits(__float2bfloat16(b.w));
    *((uint4*)dst + i) = o.v;
}

// ---------------- embedding gather + bf16 convert ----------------
__global__ void k_gather(const int* __restrict__ xs, const float* __restrict__ emb,
                         __hip_bfloat16* __restrict__ e_bf) {
    int tid = blockIdx.x * 256 + threadIdx.x;
    int r = tid >> 6, ch = tid & 63;
    int v = xs[r];
    const float4* s = (const float4*)(emb + (size_t)v * DE + ch * 8);
    float4 a = s[0], b = s[1];
    union { unsigned short u[8]; uint4 v4; } o;
    o.u[0] = bf_bits(__float2bfloat16(a.x));
    o.u[1] = bf_bits(__float2bfloat16(a.y));
    o.u[2] = bf_bits(__float2bfloat16(a.z));
    o.u[3] = bf_bits(__float2bfloat16(a.w));
    o.u[4] = bf_bits(__float2bfloat16(b.x));
    o.u[5] = bf_bits(__float2bfloat16(b.y));
    o.u[6] = bf_bits(__float2bfloat16(b.z));
    o.u[7] = bf_bits(__float2bfloat16(b.w));
    *((uint4*)(e_bf + (size_t)r * DE) + ch) = o.v4;
}

// ---------------- x_gates GEMM -> permuted bf16 layout ----------------
// xgp[t][blk64][gate][unit16][batch] : (((t*64+blk)*4+g)*16+u)*64 + b
__global__ void k_gemm_xg(const __hip_bfloat16* __restrict__ A,   // [16384][512]
                          const __hip_bfloat16* __restrict__ Bt,  // [4096][512]
                          const float* __restrict__ bih, const float* __restrict__ bhh,
                          __hip_bfloat16* __restrict__ xgp) {
    __shared__ __align__(16) __hip_bfloat16 sA[128 * 32];
    __shared__ __align__(16) __hip_bfloat16 sB[128 * 32];
    const int bm = blockIdx.x >> 5;    // 128 M-tiles
    const int bn = blockIdx.x & 31;    // 32 N-tiles
    const int tid = threadIdx.x;
    const int l = tid & 63, w = tid >> 6;
    const int wm = w >> 1, wn = w & 1;
    const int lrow = l & 15, lq = l >> 4;

    f32x4 acc[4][4] = {};

    for (int kb = 0; kb < 512; kb += 32) {
#pragma unroll
        for (int q = 0; q < 2; ++q) {
            int c = q * 256 + tid;
            int row = c >> 2, seg = c & 3;
            async_copy16(A + (size_t)(bm * 128 + row) * 512 + kb + seg * 8, &sA[c * 8]);
            async_copy16(Bt + (size_t)(bn * 128 + row) * 512 + kb + seg * 8, &sB[c * 8]);
        }
        __syncthreads();
        bf16x8 af[4], bq[4];
#pragma unroll
        for (int mt = 0; mt < 4; ++mt)
            af[mt] = *(const bf16x8*)&sA[(wm * 64 + mt * 16 + lrow) * 32 + lq * 8];
#pragma unroll
        for (int nt = 0; nt < 4; ++nt)
            bq[nt] = *(const bf16x8*)&sB[(wn * 64 + nt * 16 + lrow) * 32 + lq * 8];
#pragma unroll
        for (int mt = 0; mt < 4; ++mt)
#pragma unroll
            for (int nt = 0; nt < 4; ++nt)
                acc[mt][nt] = __builtin_amdgcn_mfma_f32_16x16x32_bf16(
                    af[mt], bq[nt], acc[mt][nt], 0, 0, 0);
        __syncthreads();
    }

#pragma unroll
    for (int nt = 0; nt < 4; ++nt) {
        int n = bn * 128 + wn * 64 + nt * 16 + lrow;
        int g = n >> 10, j = n & 1023, blk = j >> 4, u = j & 15;
        float bias = bih[n] + bhh[n];
#pragma unroll
        for (int mt = 0; mt < 4; ++mt) {
#pragma unroll
            for (int r = 0; r < 4; ++r) {
                int m = bm * 128 + wm * 64 + mt * 16 + lq * 4 + r;
                int t = m >> 6, b = m & 63;
                xgp[(((size_t)(t * NBLK + blk) * 4 + g) * 16 + u) * 64 + b] =
                    __float2bfloat16(acc[mt][nt][r] + bias);
            }
        }
    }
}

// ---------------- persistent LSTM recurrence, barrier-free tagged data-flow ----------------
// 64 blocks x 256 thr (4 waves). Block owns units 16*bk..+15 (64 gate rows, all 4 gates).
// Whh slice LDS-resident (128 KB). Wave w owns batches 16w..+15 (batch samples are
// independent -> wave-level sync only, via LSB step-parity tags in the h words).
// h double-buffered; word layout W(k,b) at ((k/32*4 + (k%32)/8)*64 + b)*8 + k%8.
__global__ void __launch_bounds__(256) k_lstm(
        const __hip_bfloat16* __restrict__ xgp,   // [256][64][4][16][64]
        const __hip_bfloat16* __restrict__ Whh,   // [4096][1024] row-major
        unsigned short* __restrict__ hbuf,        // 2 x 65536 bf16-with-LSB-tag
        float* __restrict__ out) {
    __shared__ __hip_bfloat16 sW[65536];          // 128 KB: [g4][kc32][lq4][unit16][8]
    const int tid = threadIdx.x, l = tid & 63, w = tid >> 6;
    const int lrow = l & 15, lq = l >> 4;
    const int bk = blockIdx.x;

    // Whh slice -> LDS, frag-contiguous
    for (int it = 0; it < 32; ++it) {
        int fi = it * 256 + tid;                  // 8192 16B-frags
        int n = fi & 15, lqq = (fi >> 4) & 3, kc = (fi >> 6) & 31, g = fi >> 11;
        async_copy16(Whh + (size_t)(g * DH + bk * 16 + n) * DH + kc * 32 + lqq * 8,
                     &sW[fi * 8]);
    }
    __syncthreads();

    const int b0 = w * 16 + lq * 4;
    const int abase = (lq * 64 + w * 16 + lrow) * 2;        // u64 idx within k-chunk
    const int kg = bk * 16 + lrow;                          // my unit's global k
    const int pbase = ((kg >> 5) * 4 + ((kg & 31) >> 3)) * 512 + (kg & 7);
    float creg[4] = {0.f, 0.f, 0.f, 0.f};

    for (int t = 0; t < T_STEPS; ++t) {
        const u64* hin = (const u64*)hbuf + (size_t)(t & 1) * 16384;
        unsigned short* hout = hbuf + (size_t)((t + 1) & 1) * 65536;
        const u64 expw = ((t >> 1) & 1) ? LSBMASK : 0ull;   // valid-tag for h_t
        const unsigned short wpar = (unsigned short)(((t + 1) >> 1) & 1);

        // this step's xg: all 4 gates for (unit=lrow, batches b0..b0+3)
        const __hip_bfloat16* xgt = xgp + ((size_t)t * NBLK + bk) * 4096;
        ushort4 xv0 = *(const ushort4*)(xgt + (0 * 16 + lrow) * 64 + b0);
        ushort4 xv1 = *(const ushort4*)(xgt + (1 * 16 + lrow) * 64 + b0);
        ushort4 xv2 = *(const ushort4*)(xgt + (2 * 16 + lrow) * 64 + b0);
        ushort4 xv3 = *(const ushort4*)(xgt + (3 * 16 + lrow) * 64 + b0);

        // K-loop: tagged h A-frags from LLC (8-deep speculative pipeline, spin on stale)
        u64 a0[8], a1[8];
#pragma unroll
        for (int p = 0; p < 8; ++p) {
            a0[p] = llc_load64(hin + p * 512 + abase);
            a1[p] = llc_load64(hin + p * 512 + abase + 1);
        }
        f32x4 acc[4] = {};
#pragma unroll
        for (int kc = 0; kc < 32; ++kc) {
            u64 x0 = a0[kc & 7], x1 = a1[kc & 7];
            const u64* p0 = hin + kc * 512 + abase;
            while ((((x0 ^ expw) | (x1 ^ expw)) & LSBMASK) != 0ull) {
                x0 = llc_load64(p0);
                x1 = llc_load64(p0 + 1);
            }
            union { u64 q[2]; bf16x8 v; } A;
            A.q[0] = x0; A.q[1] = x1;
#pragma unroll
            for (int g = 0; g < 4; ++g) {
                bf16x8 bf = *(const bf16x8*)&sW[(((g * 32 + kc) * 4 + lq) * 16 + lrow) * 8];
                acc[g] = __builtin_amdgcn_mfma_f32_16x16x32_bf16(A.v, bf, acc[g], 0, 0, 0);
            }
            if (kc + 8 < 32) {
                a0[kc & 7] = llc_load64(hin + (kc + 8) * 512 + abase);
                a1[kc & 7] = llc_load64(hin + (kc + 8) * 512 + abase + 1);
            }
        }

        // epilogue: lane owns (unit kg, batches b0..b0+3), all 4 gates in-lane
        const unsigned short* xi = (const unsigned short*)&xv0;
        const unsigned short* xf = (const unsigned short*)&xv1;
        const unsigned short* xg_ = (const unsigned short*)&xv2;
        const unsigned short* xo = (const unsigned short*)&xv3;
#pragma unroll
        for (int r = 0; r < 4; ++r) {
            int b = b0 + r;
            float vi = acc[0][r] + b2f(xi[r]);
            float vf = acc[1][r] + b2f(xf[r]);
            float vg = acc[2][r] + b2f(xg_[r]);
            float vo = acc[3][r] + b2f(xo[r]);
            float ig = 1.0f / (1.0f + __expf(-vi));
            float fg = 1.0f / (1.0f + __expf(-vf));
            float gg = tanhf(vg);
            float og = 1.0f / (1.0f + __expf(-vo));
            float cnew = fg * creg[r] + ig * gg;
            float hnew = og * tanhf(cnew);
            creg[r] = cnew;
            out[((size_t)t * BATCH + b) * DH + kg] = hnew;
            unsigned short hb =
                (unsigned short)((bf_bits(__float2bfloat16(hnew)) & 0xFFFEu) | wpar);
            llc_store16(hout + pbase + b * 8, hb);
            if (t == T_STEPS - 1) {
                out[(size_t)T_STEPS * BATCH * DH + (size_t)b * DH + kg] = hnew;
                out[(size_t)T_STEPS * BATCH * DH + BATCH * DH + (size_t)b * DH + kg] = cnew;
            }
        }
    }
}

extern "C" void kernel_launch(void* const* d_in, const int* in_sizes, int n_in,
                              void* d_out, int out_size, void* d_ws, size_t ws_size,
                              hipStream_t stream) {
    const int*   xs  = (const int*)d_in[0];
    const float* emb = (const float*)d_in[1];
    const float* Wih = (const float*)d_in[2];
    const float* Whh = (const float*)d_in[3];
    const float* bih = (const float*)d_in[4];
    const float* bhh = (const float*)d_in[5];
    float* out = (float*)d_out;
    char*  ws  = (char*)d_ws;

    __hip_bfloat16* Wih_bf = (__hip_bfloat16*)(ws);                  //  4 MB
    __hip_bfloat16* Whh_bf = (__hip_bfloat16*)(ws + 4194304);        //  8 MB
    __hip_bfloat16* e_bf   = (__hip_bfloat16*)(ws + 12582912);       // 16 MB
    __hip_bfloat16* xgp    = (__hip_bfloat16*)(ws + 29360128);       // 128 MB
    unsigned short* hbuf   = (unsigned short*)(ws + 163577856);      // 256 KB (2 bufs)

    k_init<<<128, 256, 0, stream>>>((u64*)hbuf);
    k_f32_to_bf16<<<1024, 256, 0, stream>>>(Wih, Wih_bf, 2097152 / 8);
    k_f32_to_bf16<<<2048, 256, 0, stream>>>(Whh, Whh_bf, 4194304 / 8);
    k_gather<<<4096, 256, 0, stream>>>(xs, emb, e_bf);
    k_gemm_xg<<<4096, 256, 0, stream>>>(e_bf, Wih_bf, bih, bhh, xgp);
    k_lstm<<<NBLK, 256, 0, stream>>>(xgp, Whh_bf, hbuf, out);
}